// Round 1
// baseline (1069.640 us; speedup 1.0000x reference)
//
#include <hip/hip_runtime.h>
#include <hip/hip_bf16.h>
#include <cmath>

#define NN 100000
#define IND 512
#define HID 64
#define NC  40

// ---------------- CSR build ----------------

__global__ __launch_bounds__(256) void init_deg_kernel(int* __restrict__ deg, int n) {
    int i = blockIdx.x * blockDim.x + threadIdx.x;
    if (i < n) deg[i] = 1;  // self-loop
}

__global__ __launch_bounds__(256) void count_kernel(const int* __restrict__ dst,
                                                    int* __restrict__ deg, int E) {
    int e = blockIdx.x * blockDim.x + threadIdx.x;
    if (e < E) atomicAdd(&deg[dst[e]], 1);
}

// single-block exclusive scan of (deg-1) -> rowptr, cursor; also dinv = rsqrt(deg)
__global__ __launch_bounds__(1024) void scan_kernel(const int* __restrict__ deg,
                                                    int* __restrict__ rowptr,
                                                    int* __restrict__ cursor,
                                                    float* __restrict__ dinv, int n) {
    __shared__ int sums[1024];
    int t = threadIdx.x;
    const int C = (n + 1023) >> 10;
    int lo = t * C;
    int hi = lo + C; if (hi > n) hi = n;
    int s = 0;
    for (int i = lo; i < hi; ++i) s += deg[i] - 1;
    sums[t] = s;
    __syncthreads();
    for (int off = 1; off < 1024; off <<= 1) {
        int v = (t >= off) ? sums[t - off] : 0;
        __syncthreads();
        sums[t] += v;
        __syncthreads();
    }
    int run = sums[t] - s;  // exclusive prefix
    for (int i = lo; i < hi; ++i) {
        rowptr[i] = run;
        cursor[i] = run;
        dinv[i] = rsqrtf((float)deg[i]);
        run += deg[i] - 1;
    }
    if (t == 1023) rowptr[n] = sums[1023];
}

__global__ __launch_bounds__(256) void fill_kernel(const int* __restrict__ src,
                                                   const int* __restrict__ dst,
                                                   int* __restrict__ cursor,
                                                   int* __restrict__ colx, int E) {
    int e = blockIdx.x * blockDim.x + threadIdx.x;
    if (e < E) {
        int d = dst[e];
        int pos = atomicAdd(&cursor[d], 1);
        colx[pos] = src[e];
    }
}

// ---------------- Layer 1 GEMM: hs = (x @ W1) * dinv[row] ----------------
// M=100000, K=512, N=64. 64x64 tile per 256-thread block, 4x4 microtile.

__global__ __launch_bounds__(256) void gemm1_kernel(const float* __restrict__ x,
                                                    const float* __restrict__ W1,
                                                    const float* __restrict__ dinv,
                                                    float* __restrict__ hs, int M) {
    __shared__ float xs[32][68];  // [k][r], padded
    __shared__ float ws[32][68];  // [k][n], padded
    int tid = threadIdx.x;
    int tx = tid & 15, ty = tid >> 4;
    int row0 = blockIdx.x * 64;

    float acc[4][4] = {};

    // x-tile load mapping: 4 threads per row, each 2x float4 (stripes of 16B)
    int xr = tid >> 2;
    int xk = (tid & 3) * 4;
    int grow = row0 + xr; if (grow > M - 1) grow = M - 1;
    const float* xbase = x + (size_t)grow * IND;
    // W-tile: 8 threads per k-row, each 2x float4
    int wk = tid >> 3;
    int wn = (tid & 7) * 4;

    for (int k0 = 0; k0 < IND; k0 += 32) {
        float4 a0 = *(const float4*)(xbase + k0 + xk);
        float4 a1 = *(const float4*)(xbase + k0 + xk + 16);
        xs[xk + 0][xr] = a0.x; xs[xk + 1][xr] = a0.y;
        xs[xk + 2][xr] = a0.z; xs[xk + 3][xr] = a0.w;
        xs[xk + 16][xr] = a1.x; xs[xk + 17][xr] = a1.y;
        xs[xk + 18][xr] = a1.z; xs[xk + 19][xr] = a1.w;

        float4 b0 = *(const float4*)(W1 + (size_t)(k0 + wk) * HID + wn);
        float4 b1 = *(const float4*)(W1 + (size_t)(k0 + wk) * HID + wn + 32);
        *(float4*)&ws[wk][wn] = b0;
        *(float4*)&ws[wk][wn + 32] = b1;
        __syncthreads();

#pragma unroll
        for (int kk = 0; kk < 32; ++kk) {
            float4 av = *(float4*)&xs[kk][ty * 4];
            float4 bv = *(float4*)&ws[kk][tx * 4];
            acc[0][0] += av.x * bv.x; acc[0][1] += av.x * bv.y;
            acc[0][2] += av.x * bv.z; acc[0][3] += av.x * bv.w;
            acc[1][0] += av.y * bv.x; acc[1][1] += av.y * bv.y;
            acc[1][2] += av.y * bv.z; acc[1][3] += av.y * bv.w;
            acc[2][0] += av.z * bv.x; acc[2][1] += av.z * bv.y;
            acc[2][2] += av.z * bv.z; acc[2][3] += av.z * bv.w;
            acc[3][0] += av.w * bv.x; acc[3][1] += av.w * bv.y;
            acc[3][2] += av.w * bv.z; acc[3][3] += av.w * bv.w;
        }
        __syncthreads();
    }

#pragma unroll
    for (int i = 0; i < 4; ++i) {
        int row = row0 + ty * 4 + i;
        if (row < M) {
            float d = dinv[row];
#pragma unroll
            for (int j = 0; j < 4; ++j)
                hs[(size_t)row * HID + tx * 4 + j] = acc[i][j] * d;
        }
    }
}

// ---------------- agg1: h1 = relu(dinv[i]*(sum_{e} hs[col[e]] + hs[i]) + b1) ----------------
// one wave per node, lane = feature (64)

__global__ __launch_bounds__(256) void agg1_kernel(const float* __restrict__ hs,
                                                   const int* __restrict__ rowptr,
                                                   const int* __restrict__ colx,
                                                   const float* __restrict__ dinv,
                                                   const float* __restrict__ b1,
                                                   float* __restrict__ h1) {
    int node = (blockIdx.x * blockDim.x + threadIdx.x) >> 6;
    int lane = threadIdx.x & 63;
    if (node >= NN) return;
    int beg = rowptr[node], end = rowptr[node + 1];
    float acc = hs[(size_t)node * HID + lane];  // self loop (already dinv-scaled)
    int e = beg;
    for (; e + 3 < end; e += 4) {
        int c0 = colx[e], c1 = colx[e + 1], c2 = colx[e + 2], c3 = colx[e + 3];
        float v0 = hs[(size_t)c0 * HID + lane];
        float v1 = hs[(size_t)c1 * HID + lane];
        float v2 = hs[(size_t)c2 * HID + lane];
        float v3 = hs[(size_t)c3 * HID + lane];
        acc += v0 + v1 + v2 + v3;
    }
    for (; e < end; ++e) acc += hs[(size_t)colx[e] * HID + lane];
    float v = acc * dinv[node] + b1[lane];
    h1[(size_t)node * HID + lane] = v > 0.f ? v : 0.f;
}

// ---------------- Layer 2 GEMM: h2s = (h1 @ W2) * dinv ----------------

__global__ __launch_bounds__(256) void gemm2_kernel(const float* __restrict__ h1,
                                                    const float* __restrict__ W2,
                                                    const float* __restrict__ dinv,
                                                    float* __restrict__ h2s, int M) {
    __shared__ float hsld[64][68];
    __shared__ float wls[64 * 40];
    int tid = threadIdx.x;
    int row0 = blockIdx.x * 64;

    int r = tid >> 2;
    int kb = (tid & 3) * 16;
    int grow = row0 + r; if (grow > M - 1) grow = M - 1;
    const float4* srcp = (const float4*)(h1 + (size_t)grow * HID + kb);
    *(float4*)&hsld[r][kb + 0] = srcp[0];
    *(float4*)&hsld[r][kb + 4] = srcp[1];
    *(float4*)&hsld[r][kb + 8] = srcp[2];
    *(float4*)&hsld[r][kb + 12] = srcp[3];
    for (int idx = tid; idx < HID * NC; idx += 256) wls[idx] = W2[idx];
    __syncthreads();

    for (int o = tid; o < 64 * NC; o += 256) {
        int rr = o / NC;
        int c = o - rr * NC;
        float s = 0.f;
#pragma unroll
        for (int k4 = 0; k4 < 16; ++k4) {
            float4 hv = *(float4*)&hsld[rr][k4 * 4];
            s += hv.x * wls[(k4 * 4 + 0) * NC + c];
            s += hv.y * wls[(k4 * 4 + 1) * NC + c];
            s += hv.z * wls[(k4 * 4 + 2) * NC + c];
            s += hv.w * wls[(k4 * 4 + 3) * NC + c];
        }
        int row = row0 + rr;
        if (row < M) h2s[(size_t)row * NC + c] = s * dinv[row];
    }
}

// ---------------- agg2 + bias + log_softmax ----------------
// one wave per node, lanes 0..39 = classes

__global__ __launch_bounds__(256) void agg2_kernel(const float* __restrict__ h2s,
                                                   const int* __restrict__ rowptr,
                                                   const int* __restrict__ colx,
                                                   const float* __restrict__ dinv,
                                                   const float* __restrict__ b2,
                                                   float* __restrict__ out) {
    int node = (blockIdx.x * blockDim.x + threadIdx.x) >> 6;
    int lane = threadIdx.x & 63;
    if (node >= NN) return;
    bool act = lane < NC;
    int beg = rowptr[node], end = rowptr[node + 1];
    float acc = act ? h2s[(size_t)node * NC + lane] : 0.f;
    int e = beg;
    for (; e + 3 < end; e += 4) {
        int c0 = colx[e], c1 = colx[e + 1], c2 = colx[e + 2], c3 = colx[e + 3];
        if (act) {
            float v0 = h2s[(size_t)c0 * NC + lane];
            float v1 = h2s[(size_t)c1 * NC + lane];
            float v2 = h2s[(size_t)c2 * NC + lane];
            float v3 = h2s[(size_t)c3 * NC + lane];
            acc += v0 + v1 + v2 + v3;
        }
    }
    for (; e < end; ++e)
        if (act) acc += h2s[(size_t)colx[e] * NC + lane];

    float v = act ? acc * dinv[node] + b2[lane] : -INFINITY;
    float m = v;
#pragma unroll
    for (int off = 32; off; off >>= 1) m = fmaxf(m, __shfl_xor(m, off));
    float ex = act ? expf(v - m) : 0.f;
    float s = ex;
#pragma unroll
    for (int off = 32; off; off >>= 1) s += __shfl_xor(s, off);
    if (act) out[(size_t)node * NC + lane] = v - m - logf(s);
}

// ---------------- launch ----------------

extern "C" void kernel_launch(void* const* d_in, const int* in_sizes, int n_in,
                              void* d_out, int out_size, void* d_ws, size_t ws_size,
                              hipStream_t stream) {
    const float* x  = (const float*)d_in[0];
    const int* ei   = (const int*)d_in[1];
    const float* W1 = (const float*)d_in[2];
    const float* b1 = (const float*)d_in[3];
    const float* W2 = (const float*)d_in[4];
    const float* b2 = (const float*)d_in[5];
    float* out = (float*)d_out;

    const int E = in_sizes[1] / 2;
    const int* src = ei;
    const int* dst = ei + E;

    // workspace carve-up
    char* p = (char*)d_ws;
    size_t off = 0;
    auto carve = [&](size_t bytes) {
        void* q = p + off;
        off = (off + bytes + 255) & ~(size_t)255;
        return q;
    };
    int* deg      = (int*)carve((size_t)NN * 4);
    int* cursor   = (int*)carve((size_t)NN * 4);
    int* rowptr   = (int*)carve((size_t)(NN + 1) * 4);
    float* dinv   = (float*)carve((size_t)NN * 4);
    int* colx     = (int*)carve((size_t)E * 4);
    float* hs     = (float*)carve((size_t)NN * HID * 4);  // reused as h2s later
    float* h1     = (float*)carve((size_t)NN * HID * 4);
    float* h2s    = hs;  // alias: hs dead after agg1

    init_deg_kernel<<<(NN + 255) / 256, 256, 0, stream>>>(deg, NN);
    count_kernel<<<(E + 255) / 256, 256, 0, stream>>>(dst, deg, E);
    scan_kernel<<<1, 1024, 0, stream>>>(deg, rowptr, cursor, dinv, NN);
    fill_kernel<<<(E + 255) / 256, 256, 0, stream>>>(src, dst, cursor, colx, E);
    gemm1_kernel<<<(NN + 63) / 64, 256, 0, stream>>>(x, W1, dinv, hs, NN);
    agg1_kernel<<<(NN + 3) / 4, 256, 0, stream>>>(hs, rowptr, colx, dinv, b1, h1);
    gemm2_kernel<<<(NN + 63) / 64, 256, 0, stream>>>(h1, W2, dinv, h2s, NN);
    agg2_kernel<<<(NN + 3) / 4, 256, 0, stream>>>(h2s, rowptr, colx, dinv, b2, out);
}

// Round 2
// 723.764 us; speedup vs baseline: 1.4779x; 1.4779x over previous
//
#include <hip/hip_runtime.h>
#include <hip/hip_bf16.h>
#include <cmath>

#define NN 100000
#define IND 512
#define HID 64
#define NC  40
#define FILL_PASSES 8
#define NODES_PER_PASS ((NN + FILL_PASSES - 1) / FILL_PASSES)
#define SCAN_CHUNK 1024
#define SCAN_BLOCKS ((NN + SCAN_CHUNK - 1) / SCAN_CHUNK)

// ---------------- CSR build ----------------

__global__ __launch_bounds__(256) void init_deg_kernel(int* __restrict__ deg, int n) {
    int i = blockIdx.x * blockDim.x + threadIdx.x;
    if (i < n) deg[i] = 1;  // self-loop
}

__global__ __launch_bounds__(256) void count_kernel(const int* __restrict__ dst,
                                                    int* __restrict__ deg, int E) {
    int e = blockIdx.x * blockDim.x + threadIdx.x;
    if (e < E) atomicAdd(&deg[dst[e]], 1);
}

// phase A: per-block partial sums of (deg-1) over SCAN_CHUNK-sized chunks
__global__ __launch_bounds__(256) void scanA_kernel(const int* __restrict__ deg,
                                                    int* __restrict__ bsum, int n) {
    __shared__ int red[256];
    int b = blockIdx.x, t = threadIdx.x;
    int base = b * SCAN_CHUNK;
    int s = 0;
    for (int i = t; i < SCAN_CHUNK; i += 256) {
        int g = base + i;
        if (g < n) s += deg[g] - 1;
    }
    red[t] = s;
    __syncthreads();
    for (int off = 128; off; off >>= 1) {
        if (t < off) red[t] += red[t + off];
        __syncthreads();
    }
    if (t == 0) bsum[b] = red[0];
}

// phase B: single small block exclusive-scans the block sums (SCAN_BLOCKS <= 128)
__global__ __launch_bounds__(128) void scanB_kernel(int* __restrict__ bsum, int nb) {
    __shared__ int sh[128];
    int t = threadIdx.x;
    int v = (t < nb) ? bsum[t] : 0;
    sh[t] = v;
    __syncthreads();
    for (int off = 1; off < 128; off <<= 1) {
        int u = (t >= off) ? sh[t - off] : 0;
        __syncthreads();
        sh[t] += u;
        __syncthreads();
    }
    if (t < nb) bsum[t] = sh[t] - v;  // exclusive
}

// phase C: per-block local exclusive scan + write rowptr/cursor/dinv
__global__ __launch_bounds__(256) void scanC_kernel(const int* __restrict__ deg,
                                                    const int* __restrict__ bsum,
                                                    int* __restrict__ rowptr,
                                                    int* __restrict__ cursor,
                                                    float* __restrict__ dinv, int n) {
    __shared__ int sh[256];
    int b = blockIdx.x, t = threadIdx.x;
    int base = b * SCAN_CHUNK + t * 4;
    int d[4];
    int s = 0;
#pragma unroll
    for (int j = 0; j < 4; ++j) {
        int g = base + j;
        d[j] = (g < n) ? deg[g] : 1;
        s += d[j] - 1;
    }
    sh[t] = s;
    __syncthreads();
    for (int off = 1; off < 256; off <<= 1) {
        int u = (t >= off) ? sh[t - off] : 0;
        __syncthreads();
        sh[t] += u;
        __syncthreads();
    }
    int run = bsum[b] + sh[t] - s;  // exclusive prefix for this thread's chunk
#pragma unroll
    for (int j = 0; j < 4; ++j) {
        int g = base + j;
        if (g < n) {
            rowptr[g] = run;
            cursor[g] = run;
            dinv[g] = rsqrtf((float)d[j]);
            run += d[j] - 1;
            if (g == n - 1) rowptr[n] = run;
        }
    }
}

// fill restricted to a dst range: confines colx writes to a small cache-resident
// window so 64B lines are fully populated before writeback (kills the 15x write
// amplification seen with the single-pass random scatter).
__global__ __launch_bounds__(256) void fill_range_kernel(const int* __restrict__ src,
                                                         const int* __restrict__ dst,
                                                         int* __restrict__ cursor,
                                                         int* __restrict__ colx,
                                                         int E, int lo, int hi) {
    int e = blockIdx.x * blockDim.x + threadIdx.x;
    if (e < E) {
        int d = dst[e];
        if (d >= lo && d < hi) {
            int pos = atomicAdd(&cursor[d], 1);
            colx[pos] = src[e];
        }
    }
}

// ---------------- Layer 1 GEMM: hs = (x @ W1) * dinv[row] ----------------
// M=100000, K=512, N=64. 64x64 tile per 256-thread block, 4x4 microtile.

__global__ __launch_bounds__(256) void gemm1_kernel(const float* __restrict__ x,
                                                    const float* __restrict__ W1,
                                                    const float* __restrict__ dinv,
                                                    float* __restrict__ hs, int M) {
    __shared__ float xs[32][68];  // [k][r], padded
    __shared__ float ws[32][68];  // [k][n], padded
    int tid = threadIdx.x;
    int tx = tid & 15, ty = tid >> 4;
    int row0 = blockIdx.x * 64;

    float acc[4][4] = {};

    int xr = tid >> 2;
    int xk = (tid & 3) * 4;
    int grow = row0 + xr; if (grow > M - 1) grow = M - 1;
    const float* xbase = x + (size_t)grow * IND;
    int wk = tid >> 3;
    int wn = (tid & 7) * 4;

    for (int k0 = 0; k0 < IND; k0 += 32) {
        float4 a0 = *(const float4*)(xbase + k0 + xk);
        float4 a1 = *(const float4*)(xbase + k0 + xk + 16);
        xs[xk + 0][xr] = a0.x; xs[xk + 1][xr] = a0.y;
        xs[xk + 2][xr] = a0.z; xs[xk + 3][xr] = a0.w;
        xs[xk + 16][xr] = a1.x; xs[xk + 17][xr] = a1.y;
        xs[xk + 18][xr] = a1.z; xs[xk + 19][xr] = a1.w;

        float4 b0 = *(const float4*)(W1 + (size_t)(k0 + wk) * HID + wn);
        float4 b1 = *(const float4*)(W1 + (size_t)(k0 + wk) * HID + wn + 32);
        *(float4*)&ws[wk][wn] = b0;
        *(float4*)&ws[wk][wn + 32] = b1;
        __syncthreads();

#pragma unroll
        for (int kk = 0; kk < 32; ++kk) {
            float4 av = *(float4*)&xs[kk][ty * 4];
            float4 bv = *(float4*)&ws[kk][tx * 4];
            acc[0][0] += av.x * bv.x; acc[0][1] += av.x * bv.y;
            acc[0][2] += av.x * bv.z; acc[0][3] += av.x * bv.w;
            acc[1][0] += av.y * bv.x; acc[1][1] += av.y * bv.y;
            acc[1][2] += av.y * bv.z; acc[1][3] += av.y * bv.w;
            acc[2][0] += av.z * bv.x; acc[2][1] += av.z * bv.y;
            acc[2][2] += av.z * bv.z; acc[2][3] += av.z * bv.w;
            acc[3][0] += av.w * bv.x; acc[3][1] += av.w * bv.y;
            acc[3][2] += av.w * bv.z; acc[3][3] += av.w * bv.w;
        }
        __syncthreads();
    }

#pragma unroll
    for (int i = 0; i < 4; ++i) {
        int row = row0 + ty * 4 + i;
        if (row < M) {
            float d = dinv[row];
#pragma unroll
            for (int j = 0; j < 4; ++j)
                hs[(size_t)row * HID + tx * 4 + j] = acc[i][j] * d;
        }
    }
}

// ---------------- agg1: h1 = relu(dinv[i]*(sum_{e} hs[col[e]] + hs[i]) + b1) ----------------

__global__ __launch_bounds__(256) void agg1_kernel(const float* __restrict__ hs,
                                                   const int* __restrict__ rowptr,
                                                   const int* __restrict__ colx,
                                                   const float* __restrict__ dinv,
                                                   const float* __restrict__ b1,
                                                   float* __restrict__ h1) {
    int node = (blockIdx.x * blockDim.x + threadIdx.x) >> 6;
    int lane = threadIdx.x & 63;
    if (node >= NN) return;
    int beg = rowptr[node], end = rowptr[node + 1];
    float acc = hs[(size_t)node * HID + lane];
    int e = beg;
    for (; e + 3 < end; e += 4) {
        int c0 = colx[e], c1 = colx[e + 1], c2 = colx[e + 2], c3 = colx[e + 3];
        float v0 = hs[(size_t)c0 * HID + lane];
        float v1 = hs[(size_t)c1 * HID + lane];
        float v2 = hs[(size_t)c2 * HID + lane];
        float v3 = hs[(size_t)c3 * HID + lane];
        acc += v0 + v1 + v2 + v3;
    }
    for (; e < end; ++e) acc += hs[(size_t)colx[e] * HID + lane];
    float v = acc * dinv[node] + b1[lane];
    h1[(size_t)node * HID + lane] = v > 0.f ? v : 0.f;
}

// ---------------- Layer 2 GEMM: h2s = (h1 @ W2) * dinv ----------------

__global__ __launch_bounds__(256) void gemm2_kernel(const float* __restrict__ h1,
                                                    const float* __restrict__ W2,
                                                    const float* __restrict__ dinv,
                                                    float* __restrict__ h2s, int M) {
    __shared__ float hsld[64][68];
    __shared__ float wls[64 * 40];
    int tid = threadIdx.x;
    int row0 = blockIdx.x * 64;

    int r = tid >> 2;
    int kb = (tid & 3) * 16;
    int grow = row0 + r; if (grow > M - 1) grow = M - 1;
    const float4* srcp = (const float4*)(h1 + (size_t)grow * HID + kb);
    *(float4*)&hsld[r][kb + 0] = srcp[0];
    *(float4*)&hsld[r][kb + 4] = srcp[1];
    *(float4*)&hsld[r][kb + 8] = srcp[2];
    *(float4*)&hsld[r][kb + 12] = srcp[3];
    for (int idx = tid; idx < HID * NC; idx += 256) wls[idx] = W2[idx];
    __syncthreads();

    for (int o = tid; o < 64 * NC; o += 256) {
        int rr = o / NC;
        int c = o - rr * NC;
        float s = 0.f;
#pragma unroll
        for (int k4 = 0; k4 < 16; ++k4) {
            float4 hv = *(float4*)&hsld[rr][k4 * 4];
            s += hv.x * wls[(k4 * 4 + 0) * NC + c];
            s += hv.y * wls[(k4 * 4 + 1) * NC + c];
            s += hv.z * wls[(k4 * 4 + 2) * NC + c];
            s += hv.w * wls[(k4 * 4 + 3) * NC + c];
        }
        int row = row0 + rr;
        if (row < M) h2s[(size_t)row * NC + c] = s * dinv[row];
    }
}

// ---------------- agg2 + bias + log_softmax ----------------

__global__ __launch_bounds__(256) void agg2_kernel(const float* __restrict__ h2s,
                                                   const int* __restrict__ rowptr,
                                                   const int* __restrict__ colx,
                                                   const float* __restrict__ dinv,
                                                   const float* __restrict__ b2,
                                                   float* __restrict__ out) {
    int node = (blockIdx.x * blockDim.x + threadIdx.x) >> 6;
    int lane = threadIdx.x & 63;
    if (node >= NN) return;
    bool act = lane < NC;
    int beg = rowptr[node], end = rowptr[node + 1];
    float acc = act ? h2s[(size_t)node * NC + lane] : 0.f;
    int e = beg;
    for (; e + 3 < end; e += 4) {
        int c0 = colx[e], c1 = colx[e + 1], c2 = colx[e + 2], c3 = colx[e + 3];
        if (act) {
            float v0 = h2s[(size_t)c0 * NC + lane];
            float v1 = h2s[(size_t)c1 * NC + lane];
            float v2 = h2s[(size_t)c2 * NC + lane];
            float v3 = h2s[(size_t)c3 * NC + lane];
            acc += v0 + v1 + v2 + v3;
        }
    }
    for (; e < end; ++e)
        if (act) acc += h2s[(size_t)colx[e] * NC + lane];

    float v = act ? acc * dinv[node] + b2[lane] : -INFINITY;
    float m = v;
#pragma unroll
    for (int off = 32; off; off >>= 1) m = fmaxf(m, __shfl_xor(m, off));
    float ex = act ? expf(v - m) : 0.f;
    float s = ex;
#pragma unroll
    for (int off = 32; off; off >>= 1) s += __shfl_xor(s, off);
    if (act) out[(size_t)node * NC + lane] = v - m - logf(s);
}

// ---------------- launch ----------------

extern "C" void kernel_launch(void* const* d_in, const int* in_sizes, int n_in,
                              void* d_out, int out_size, void* d_ws, size_t ws_size,
                              hipStream_t stream) {
    const float* x  = (const float*)d_in[0];
    const int* ei   = (const int*)d_in[1];
    const float* W1 = (const float*)d_in[2];
    const float* b1 = (const float*)d_in[3];
    const float* W2 = (const float*)d_in[4];
    const float* b2 = (const float*)d_in[5];
    float* out = (float*)d_out;

    const int E = in_sizes[1] / 2;
    const int* src = ei;
    const int* dst = ei + E;

    char* p = (char*)d_ws;
    size_t off = 0;
    auto carve = [&](size_t bytes) {
        void* q = p + off;
        off = (off + bytes + 255) & ~(size_t)255;
        return q;
    };
    int* deg      = (int*)carve((size_t)NN * 4);
    int* cursor   = (int*)carve((size_t)NN * 4);
    int* rowptr   = (int*)carve((size_t)(NN + 1) * 4);
    float* dinv   = (float*)carve((size_t)NN * 4);
    int* bsum     = (int*)carve((size_t)SCAN_BLOCKS * 4);
    int* colx     = (int*)carve((size_t)E * 4);
    float* hs     = (float*)carve((size_t)NN * HID * 4);  // reused as h2s later
    float* h1     = (float*)carve((size_t)NN * HID * 4);
    float* h2s    = hs;  // alias: hs dead after agg1

    init_deg_kernel<<<(NN + 255) / 256, 256, 0, stream>>>(deg, NN);
    count_kernel<<<(E + 255) / 256, 256, 0, stream>>>(dst, deg, E);
    scanA_kernel<<<SCAN_BLOCKS, 256, 0, stream>>>(deg, bsum, NN);
    scanB_kernel<<<1, 128, 0, stream>>>(bsum, SCAN_BLOCKS);
    scanC_kernel<<<SCAN_BLOCKS, 256, 0, stream>>>(deg, bsum, rowptr, cursor, dinv, NN);
    for (int pass = 0; pass < FILL_PASSES; ++pass) {
        int lo = pass * NODES_PER_PASS;
        int hi = lo + NODES_PER_PASS; if (hi > NN) hi = NN;
        fill_range_kernel<<<(E + 255) / 256, 256, 0, stream>>>(src, dst, cursor, colx, E, lo, hi);
    }
    gemm1_kernel<<<(NN + 63) / 64, 256, 0, stream>>>(x, W1, dinv, hs, NN);
    agg1_kernel<<<(NN + 3) / 4, 256, 0, stream>>>(hs, rowptr, colx, dinv, b1, h1);
    gemm2_kernel<<<(NN + 63) / 64, 256, 0, stream>>>(h1, W2, dinv, h2s, NN);
    agg2_kernel<<<(NN + 3) / 4, 256, 0, stream>>>(h2s, rowptr, colx, dinv, b2, out);
}

// Round 3
// 517.186 us; speedup vs baseline: 2.0682x; 1.3994x over previous
//
#include <hip/hip_runtime.h>
#include <hip/hip_bf16.h>
#include <cmath>

#define NN 100000
#define IND 512
#define HID 64
#define NC  40
#define BWN 256                      // nodes per bucket
#define NBKT ((NN + BWN - 1) / BWN)  // 391
#define NBIN_BLOCKS 100

// ---------------- CSR build: two-level bucket sort ----------------

__global__ __launch_bounds__(256) void zero_kernel(int* __restrict__ ghist, int n) {
    int i = blockIdx.x * blockDim.x + threadIdx.x;
    if (i < n) ghist[i] = 0;
}

// P0: global bucket histogram (LDS-privatized)
__global__ __launch_bounds__(256) void bhist_kernel(const int* __restrict__ dst,
                                                    int* __restrict__ ghist, int E) {
    __shared__ int hist[NBKT];
    int t = threadIdx.x;
    for (int i = t; i < NBKT; i += 256) hist[i] = 0;
    __syncthreads();
    for (int e = blockIdx.x * 256 + t; e < E; e += gridDim.x * 256)
        atomicAdd(&hist[dst[e] >> 8], 1);
    __syncthreads();
    for (int i = t; i < NBKT; i += 256)
        if (hist[i]) atomicAdd(&ghist[i], hist[i]);
}

// exclusive scan of 391 bucket counts -> bbase (layout for both staging and colx)
__global__ __launch_bounds__(512) void bscan_kernel(const int* __restrict__ ghist,
                                                    int* __restrict__ bbase,
                                                    int* __restrict__ gcursor) {
    __shared__ int sh[512];
    int t = threadIdx.x;
    int v = (t < NBKT) ? ghist[t] : 0;
    sh[t] = v;
    __syncthreads();
    for (int off = 1; off < 512; off <<= 1) {
        int u = (t >= off) ? sh[t - off] : 0;
        __syncthreads();
        sh[t] += u;
        __syncthreads();
    }
    int ex = sh[t] - v;
    if (t < NBKT) { bbase[t] = ex; gcursor[t] = ex; }
    if (t == NBKT - 1) bbase[NBKT] = ex + v;
}

// P1: bin edges into bucket-contiguous staging as packed (dst_local<<17)|src.
// Per-block LDS histogram -> one global atomic per (block,bucket) reserving a
// contiguous chunk (~330B) -> chunked, line-friendly writes.
__global__ __launch_bounds__(512) void bin_kernel(const int* __restrict__ src,
                                                  const int* __restrict__ dst,
                                                  int* __restrict__ gcursor,
                                                  int* __restrict__ packed, int E) {
    __shared__ int hist[NBKT], base[NBKT], cur[NBKT];
    int b = blockIdx.x, t = threadIdx.x;
    int epb = (E + gridDim.x - 1) / gridDim.x;
    int lo = b * epb;
    int hi = lo + epb; if (hi > E) hi = E;
    for (int i = t; i < NBKT; i += 512) { hist[i] = 0; cur[i] = 0; }
    __syncthreads();
    for (int e = lo + t; e < hi; e += 512) atomicAdd(&hist[dst[e] >> 8], 1);
    __syncthreads();
    for (int i = t; i < NBKT; i += 512)
        if (hist[i]) base[i] = atomicAdd(&gcursor[i], hist[i]);
    __syncthreads();
    for (int e = lo + t; e < hi; e += 512) {
        int d = dst[e], s = src[e];
        int bk = d >> 8;
        int pos = base[bk] + atomicAdd(&cur[bk], 1);
        packed[pos] = ((d & 255) << 17) | s;
    }
}

// P2: one block per bucket. LDS histogram+scan over the bucket's 256 nodes ->
// rowptr/dinv coalesced; colx scatter confined to the bucket's ~33KB L2 span.
__global__ __launch_bounds__(256) void csr_bucket_kernel(const int* __restrict__ packed,
                                                         const int* __restrict__ bbase,
                                                         int* __restrict__ rowptr,
                                                         int* __restrict__ colx,
                                                         float* __restrict__ dinv, int E) {
    __shared__ int hist[BWN], pfx[BWN], cur[BWN];
    int b = blockIdx.x, t = threadIdx.x;
    int nlo = b * BWN;
    int ncnt = NN - nlo; if (ncnt > BWN) ncnt = BWN;
    int ebeg = bbase[b], eend = bbase[b + 1];
    hist[t] = 0;
    __syncthreads();
    for (int e = ebeg + t; e < eend; e += 256) atomicAdd(&hist[packed[e] >> 17], 1);
    __syncthreads();
    int h = hist[t];
    pfx[t] = h;
    __syncthreads();
    for (int off = 1; off < 256; off <<= 1) {
        int u = (t >= off) ? pfx[t - off] : 0;
        __syncthreads();
        pfx[t] += u;
        __syncthreads();
    }
    int excl = pfx[t] - h;
    cur[t] = excl;
    int g = nlo + t;
    if (t < ncnt) {
        rowptr[g] = ebeg + excl;
        dinv[g] = rsqrtf((float)(h + 1));  // +1 self-loop
    }
    if (b == 0 && t == 0) rowptr[NN] = E;
    __syncthreads();
    for (int e = ebeg + t; e < eend; e += 256) {
        int p = packed[e];
        int dl = p >> 17;
        int s = p & 0x1FFFF;
        int pos = ebeg + atomicAdd(&cur[dl], 1);
        colx[pos] = s;
    }
}

// ---------------- Layer 1 GEMM: hs = (x @ W1) * dinv[row] ----------------

__global__ __launch_bounds__(256) void gemm1_kernel(const float* __restrict__ x,
                                                    const float* __restrict__ W1,
                                                    const float* __restrict__ dinv,
                                                    float* __restrict__ hs, int M) {
    __shared__ float xs[32][68];
    __shared__ float ws[32][68];
    int tid = threadIdx.x;
    int tx = tid & 15, ty = tid >> 4;
    int row0 = blockIdx.x * 64;

    float acc[4][4] = {};

    int xr = tid >> 2;
    int xk = (tid & 3) * 4;
    int grow = row0 + xr; if (grow > M - 1) grow = M - 1;
    const float* xbase = x + (size_t)grow * IND;
    int wk = tid >> 3;
    int wn = (tid & 7) * 4;

    for (int k0 = 0; k0 < IND; k0 += 32) {
        float4 a0 = *(const float4*)(xbase + k0 + xk);
        float4 a1 = *(const float4*)(xbase + k0 + xk + 16);
        xs[xk + 0][xr] = a0.x; xs[xk + 1][xr] = a0.y;
        xs[xk + 2][xr] = a0.z; xs[xk + 3][xr] = a0.w;
        xs[xk + 16][xr] = a1.x; xs[xk + 17][xr] = a1.y;
        xs[xk + 18][xr] = a1.z; xs[xk + 19][xr] = a1.w;

        float4 b0 = *(const float4*)(W1 + (size_t)(k0 + wk) * HID + wn);
        float4 b1 = *(const float4*)(W1 + (size_t)(k0 + wk) * HID + wn + 32);
        *(float4*)&ws[wk][wn] = b0;
        *(float4*)&ws[wk][wn + 32] = b1;
        __syncthreads();

#pragma unroll
        for (int kk = 0; kk < 32; ++kk) {
            float4 av = *(float4*)&xs[kk][ty * 4];
            float4 bv = *(float4*)&ws[kk][tx * 4];
            acc[0][0] += av.x * bv.x; acc[0][1] += av.x * bv.y;
            acc[0][2] += av.x * bv.z; acc[0][3] += av.x * bv.w;
            acc[1][0] += av.y * bv.x; acc[1][1] += av.y * bv.y;
            acc[1][2] += av.y * bv.z; acc[1][3] += av.y * bv.w;
            acc[2][0] += av.z * bv.x; acc[2][1] += av.z * bv.y;
            acc[2][2] += av.z * bv.z; acc[2][3] += av.z * bv.w;
            acc[3][0] += av.w * bv.x; acc[3][1] += av.w * bv.y;
            acc[3][2] += av.w * bv.z; acc[3][3] += av.w * bv.w;
        }
        __syncthreads();
    }

#pragma unroll
    for (int i = 0; i < 4; ++i) {
        int row = row0 + ty * 4 + i;
        if (row < M) {
            float d = dinv[row];
#pragma unroll
            for (int j = 0; j < 4; ++j)
                hs[(size_t)row * HID + tx * 4 + j] = acc[i][j] * d;
        }
    }
}

// ---------------- agg1 ----------------

__global__ __launch_bounds__(256) void agg1_kernel(const float* __restrict__ hs,
                                                   const int* __restrict__ rowptr,
                                                   const int* __restrict__ colx,
                                                   const float* __restrict__ dinv,
                                                   const float* __restrict__ b1,
                                                   float* __restrict__ h1) {
    int node = (blockIdx.x * blockDim.x + threadIdx.x) >> 6;
    int lane = threadIdx.x & 63;
    if (node >= NN) return;
    int beg = rowptr[node], end = rowptr[node + 1];
    float acc = hs[(size_t)node * HID + lane];
    int e = beg;
    for (; e + 3 < end; e += 4) {
        int c0 = colx[e], c1 = colx[e + 1], c2 = colx[e + 2], c3 = colx[e + 3];
        float v0 = hs[(size_t)c0 * HID + lane];
        float v1 = hs[(size_t)c1 * HID + lane];
        float v2 = hs[(size_t)c2 * HID + lane];
        float v3 = hs[(size_t)c3 * HID + lane];
        acc += v0 + v1 + v2 + v3;
    }
    for (; e < end; ++e) acc += hs[(size_t)colx[e] * HID + lane];
    float v = acc * dinv[node] + b1[lane];
    h1[(size_t)node * HID + lane] = v > 0.f ? v : 0.f;
}

// ---------------- Layer 2 GEMM ----------------

__global__ __launch_bounds__(256) void gemm2_kernel(const float* __restrict__ h1,
                                                    const float* __restrict__ W2,
                                                    const float* __restrict__ dinv,
                                                    float* __restrict__ h2s, int M) {
    __shared__ float hsld[64][68];
    __shared__ float wls[64 * 40];
    int tid = threadIdx.x;
    int row0 = blockIdx.x * 64;

    int r = tid >> 2;
    int kb = (tid & 3) * 16;
    int grow = row0 + r; if (grow > M - 1) grow = M - 1;
    const float4* srcp = (const float4*)(h1 + (size_t)grow * HID + kb);
    *(float4*)&hsld[r][kb + 0] = srcp[0];
    *(float4*)&hsld[r][kb + 4] = srcp[1];
    *(float4*)&hsld[r][kb + 8] = srcp[2];
    *(float4*)&hsld[r][kb + 12] = srcp[3];
    for (int idx = tid; idx < HID * NC; idx += 256) wls[idx] = W2[idx];
    __syncthreads();

    for (int o = tid; o < 64 * NC; o += 256) {
        int rr = o / NC;
        int c = o - rr * NC;
        float s = 0.f;
#pragma unroll
        for (int k4 = 0; k4 < 16; ++k4) {
            float4 hv = *(float4*)&hsld[rr][k4 * 4];
            s += hv.x * wls[(k4 * 4 + 0) * NC + c];
            s += hv.y * wls[(k4 * 4 + 1) * NC + c];
            s += hv.z * wls[(k4 * 4 + 2) * NC + c];
            s += hv.w * wls[(k4 * 4 + 3) * NC + c];
        }
        int row = row0 + rr;
        if (row < M) h2s[(size_t)row * NC + c] = s * dinv[row];
    }
}

// ---------------- agg2 + bias + log_softmax ----------------

__global__ __launch_bounds__(256) void agg2_kernel(const float* __restrict__ h2s,
                                                   const int* __restrict__ rowptr,
                                                   const int* __restrict__ colx,
                                                   const float* __restrict__ dinv,
                                                   const float* __restrict__ b2,
                                                   float* __restrict__ out) {
    int node = (blockIdx.x * blockDim.x + threadIdx.x) >> 6;
    int lane = threadIdx.x & 63;
    if (node >= NN) return;
    bool act = lane < NC;
    int beg = rowptr[node], end = rowptr[node + 1];
    float acc = act ? h2s[(size_t)node * NC + lane] : 0.f;
    int e = beg;
    for (; e + 3 < end; e += 4) {
        int c0 = colx[e], c1 = colx[e + 1], c2 = colx[e + 2], c3 = colx[e + 3];
        if (act) {
            float v0 = h2s[(size_t)c0 * NC + lane];
            float v1 = h2s[(size_t)c1 * NC + lane];
            float v2 = h2s[(size_t)c2 * NC + lane];
            float v3 = h2s[(size_t)c3 * NC + lane];
            acc += v0 + v1 + v2 + v3;
        }
    }
    for (; e < end; ++e)
        if (act) acc += h2s[(size_t)colx[e] * NC + lane];

    float v = act ? acc * dinv[node] + b2[lane] : -INFINITY;
    float m = v;
#pragma unroll
    for (int off = 32; off; off >>= 1) m = fmaxf(m, __shfl_xor(m, off));
    float ex = act ? expf(v - m) : 0.f;
    float s = ex;
#pragma unroll
    for (int off = 32; off; off >>= 1) s += __shfl_xor(s, off);
    if (act) out[(size_t)node * NC + lane] = v - m - logf(s);
}

// ---------------- launch ----------------

extern "C" void kernel_launch(void* const* d_in, const int* in_sizes, int n_in,
                              void* d_out, int out_size, void* d_ws, size_t ws_size,
                              hipStream_t stream) {
    const float* x  = (const float*)d_in[0];
    const int* ei   = (const int*)d_in[1];
    const float* W1 = (const float*)d_in[2];
    const float* b1 = (const float*)d_in[3];
    const float* W2 = (const float*)d_in[4];
    const float* b2 = (const float*)d_in[5];
    float* out = (float*)d_out;

    const int E = in_sizes[1] / 2;
    const int* src = ei;
    const int* dst = ei + E;

    char* p = (char*)d_ws;
    size_t off = 0;
    auto carve = [&](size_t bytes) {
        void* q = p + off;
        off = (off + bytes + 255) & ~(size_t)255;
        return q;
    };
    int* ghist    = (int*)carve((size_t)NBKT * 4);
    int* bbase    = (int*)carve((size_t)(NBKT + 1) * 4);
    int* gcursor  = (int*)carve((size_t)NBKT * 4);
    int* rowptr   = (int*)carve((size_t)(NN + 1) * 4);
    float* dinv   = (float*)carve((size_t)NN * 4);
    int* colx     = (int*)carve((size_t)E * 4);
    float* hs     = (float*)carve((size_t)NN * HID * 4);  // reused as h2s
    float* h1     = (float*)carve((size_t)NN * HID * 4);
    float* h2s    = hs;           // hs dead after agg1
    int* packed   = (int*)h1;     // staging; dead before agg1 writes h1

    zero_kernel<<<(NBKT + 255) / 256, 256, 0, stream>>>(ghist, NBKT);
    bhist_kernel<<<256, 256, 0, stream>>>(dst, ghist, E);
    bscan_kernel<<<1, 512, 0, stream>>>(ghist, bbase, gcursor);
    bin_kernel<<<NBIN_BLOCKS, 512, 0, stream>>>(src, dst, gcursor, packed, E);
    csr_bucket_kernel<<<NBKT, 256, 0, stream>>>(packed, bbase, rowptr, colx, dinv, E);
    gemm1_kernel<<<(NN + 63) / 64, 256, 0, stream>>>(x, W1, dinv, hs, NN);
    agg1_kernel<<<(NN + 3) / 4, 256, 0, stream>>>(hs, rowptr, colx, dinv, b1, h1);
    gemm2_kernel<<<(NN + 63) / 64, 256, 0, stream>>>(h1, W2, dinv, h2s, NN);
    agg2_kernel<<<(NN + 3) / 4, 256, 0, stream>>>(h2s, rowptr, colx, dinv, b2, out);
}

// Round 4
// 427.243 us; speedup vs baseline: 2.5036x; 1.2105x over previous
//
#include <hip/hip_runtime.h>
#include <hip/hip_bf16.h>
#include <cmath>

#define NN 100000
#define IND 512
#define HID 64
#define NC  40
#define BWN 256                      // nodes per bucket
#define NBKT ((NN + BWN - 1) / BWN)  // 391
#define NBIN_BLOCKS 100

typedef unsigned int uint32;

__device__ inline float bf_lo(uint32 u) { return __uint_as_float(u << 16); }
__device__ inline float bf_hi(uint32 u) { return __uint_as_float(u & 0xFFFF0000u); }
__device__ inline uint32 f2bf(float f) {
    uint32 u = __float_as_uint(f);
    return (u + 0x7FFFu + ((u >> 16) & 1u)) >> 16;  // RNE
}
__device__ inline uint32 pack2bf(float a, float b) { return f2bf(a) | (f2bf(b) << 16); }

// ---------------- CSR build: two-level bucket sort ----------------

__global__ __launch_bounds__(256) void zero_kernel(int* __restrict__ ghist, int n) {
    int i = blockIdx.x * blockDim.x + threadIdx.x;
    if (i < n) ghist[i] = 0;
}

__global__ __launch_bounds__(256) void bhist_kernel(const int* __restrict__ dst,
                                                    int* __restrict__ ghist, int E) {
    __shared__ int hist[NBKT];
    int t = threadIdx.x;
    for (int i = t; i < NBKT; i += 256) hist[i] = 0;
    __syncthreads();
    for (int e = blockIdx.x * 256 + t; e < E; e += gridDim.x * 256)
        atomicAdd(&hist[dst[e] >> 8], 1);
    __syncthreads();
    for (int i = t; i < NBKT; i += 256)
        if (hist[i]) atomicAdd(&ghist[i], hist[i]);
}

__global__ __launch_bounds__(512) void bscan_kernel(const int* __restrict__ ghist,
                                                    int* __restrict__ bbase,
                                                    int* __restrict__ gcursor) {
    __shared__ int sh[512];
    int t = threadIdx.x;
    int v = (t < NBKT) ? ghist[t] : 0;
    sh[t] = v;
    __syncthreads();
    for (int off = 1; off < 512; off <<= 1) {
        int u = (t >= off) ? sh[t - off] : 0;
        __syncthreads();
        sh[t] += u;
        __syncthreads();
    }
    int ex = sh[t] - v;
    if (t < NBKT) { bbase[t] = ex; gcursor[t] = ex; }
    if (t == NBKT - 1) bbase[NBKT] = ex + v;
}

__global__ __launch_bounds__(512) void bin_kernel(const int* __restrict__ src,
                                                  const int* __restrict__ dst,
                                                  int* __restrict__ gcursor,
                                                  int* __restrict__ packed, int E) {
    __shared__ int hist[NBKT], base[NBKT], cur[NBKT];
    int b = blockIdx.x, t = threadIdx.x;
    int epb = (E + gridDim.x - 1) / gridDim.x;
    int lo = b * epb;
    int hi = lo + epb; if (hi > E) hi = E;
    for (int i = t; i < NBKT; i += 512) { hist[i] = 0; cur[i] = 0; }
    __syncthreads();
    for (int e = lo + t; e < hi; e += 512) atomicAdd(&hist[dst[e] >> 8], 1);
    __syncthreads();
    for (int i = t; i < NBKT; i += 512)
        if (hist[i]) base[i] = atomicAdd(&gcursor[i], hist[i]);
    __syncthreads();
    for (int e = lo + t; e < hi; e += 512) {
        int d = dst[e], s = src[e];
        int bk = d >> 8;
        int pos = base[bk] + atomicAdd(&cur[bk], 1);
        packed[pos] = ((d & 255) << 17) | s;
    }
}

__global__ __launch_bounds__(256) void csr_bucket_kernel(const int* __restrict__ packed,
                                                         const int* __restrict__ bbase,
                                                         int* __restrict__ rowptr,
                                                         int* __restrict__ colx,
                                                         float* __restrict__ dinv, int E) {
    __shared__ int hist[BWN], pfx[BWN], cur[BWN];
    int b = blockIdx.x, t = threadIdx.x;
    int nlo = b * BWN;
    int ncnt = NN - nlo; if (ncnt > BWN) ncnt = BWN;
    int ebeg = bbase[b], eend = bbase[b + 1];
    hist[t] = 0;
    __syncthreads();
    for (int e = ebeg + t; e < eend; e += 256) atomicAdd(&hist[packed[e] >> 17], 1);
    __syncthreads();
    int h = hist[t];
    pfx[t] = h;
    __syncthreads();
    for (int off = 1; off < 256; off <<= 1) {
        int u = (t >= off) ? pfx[t - off] : 0;
        __syncthreads();
        pfx[t] += u;
        __syncthreads();
    }
    int excl = pfx[t] - h;
    cur[t] = excl;
    int g = nlo + t;
    if (t < ncnt) {
        rowptr[g] = ebeg + excl;
        dinv[g] = rsqrtf((float)(h + 1));  // +1 self-loop
    }
    if (b == 0 && t == 0) rowptr[NN] = E;
    __syncthreads();
    for (int e = ebeg + t; e < eend; e += 256) {
        int p = packed[e];
        int dl = p >> 17;
        int s = p & 0x1FFFF;
        int pos = ebeg + atomicAdd(&cur[dl], 1);
        colx[pos] = s;
    }
}

// ---------------- Layer 1 GEMM: hs(bf16) = (x @ W1) * dinv[row] ----------------

__global__ __launch_bounds__(256) void gemm1_kernel(const float* __restrict__ x,
                                                    const float* __restrict__ W1,
                                                    const float* __restrict__ dinv,
                                                    uint32* __restrict__ hs, int M) {
    __shared__ float xs[32][68];
    __shared__ float ws[32][68];
    int tid = threadIdx.x;
    int tx = tid & 15, ty = tid >> 4;
    int row0 = blockIdx.x * 64;

    float acc[4][4] = {};

    int xr = tid >> 2;
    int xk = (tid & 3) * 4;
    int grow = row0 + xr; if (grow > M - 1) grow = M - 1;
    const float* xbase = x + (size_t)grow * IND;
    int wk = tid >> 3;
    int wn = (tid & 7) * 4;

    for (int k0 = 0; k0 < IND; k0 += 32) {
        float4 a0 = *(const float4*)(xbase + k0 + xk);
        float4 a1 = *(const float4*)(xbase + k0 + xk + 16);
        xs[xk + 0][xr] = a0.x; xs[xk + 1][xr] = a0.y;
        xs[xk + 2][xr] = a0.z; xs[xk + 3][xr] = a0.w;
        xs[xk + 16][xr] = a1.x; xs[xk + 17][xr] = a1.y;
        xs[xk + 18][xr] = a1.z; xs[xk + 19][xr] = a1.w;

        float4 b0 = *(const float4*)(W1 + (size_t)(k0 + wk) * HID + wn);
        float4 b1 = *(const float4*)(W1 + (size_t)(k0 + wk) * HID + wn + 32);
        *(float4*)&ws[wk][wn] = b0;
        *(float4*)&ws[wk][wn + 32] = b1;
        __syncthreads();

#pragma unroll
        for (int kk = 0; kk < 32; ++kk) {
            float4 av = *(float4*)&xs[kk][ty * 4];
            float4 bv = *(float4*)&ws[kk][tx * 4];
            acc[0][0] += av.x * bv.x; acc[0][1] += av.x * bv.y;
            acc[0][2] += av.x * bv.z; acc[0][3] += av.x * bv.w;
            acc[1][0] += av.y * bv.x; acc[1][1] += av.y * bv.y;
            acc[1][2] += av.y * bv.z; acc[1][3] += av.y * bv.w;
            acc[2][0] += av.z * bv.x; acc[2][1] += av.z * bv.y;
            acc[2][2] += av.z * bv.z; acc[2][3] += av.z * bv.w;
            acc[3][0] += av.w * bv.x; acc[3][1] += av.w * bv.y;
            acc[3][2] += av.w * bv.z; acc[3][3] += av.w * bv.w;
        }
        __syncthreads();
    }

#pragma unroll
    for (int i = 0; i < 4; ++i) {
        int row = row0 + ty * 4 + i;
        if (row < M) {
            float d = dinv[row];
            uint2 w;
            w.x = pack2bf(acc[i][0] * d, acc[i][1] * d);
            w.y = pack2bf(acc[i][2] * d, acc[i][3] * d);
            *(uint2*)(hs + (size_t)row * 32 + tx * 2) = w;
        }
    }
}

// ---------------- agg1: half-wave per node, bf16 gather, f32 accum ----------------

__global__ __launch_bounds__(256) void agg1_kernel(const uint32* __restrict__ hs,
                                                   const int* __restrict__ rowptr,
                                                   const int* __restrict__ colx,
                                                   const float* __restrict__ dinv,
                                                   const float* __restrict__ b1,
                                                   float* __restrict__ h1) {
    int node = (blockIdx.x * blockDim.x + threadIdx.x) >> 5;
    int l = threadIdx.x & 31;
    if (node >= NN) return;
    int beg = rowptr[node], end = rowptr[node + 1];
    uint32 u = hs[(size_t)node * 32 + l];  // self (already dinv-scaled)
    float a0 = bf_lo(u), a1 = bf_hi(u);
    int e = beg;
    for (; e + 3 < end; e += 4) {
        int c0 = colx[e], c1 = colx[e + 1], c2 = colx[e + 2], c3 = colx[e + 3];
        uint32 u0 = hs[(size_t)c0 * 32 + l];
        uint32 u1 = hs[(size_t)c1 * 32 + l];
        uint32 u2 = hs[(size_t)c2 * 32 + l];
        uint32 u3 = hs[(size_t)c3 * 32 + l];
        a0 += bf_lo(u0) + bf_lo(u1) + bf_lo(u2) + bf_lo(u3);
        a1 += bf_hi(u0) + bf_hi(u1) + bf_hi(u2) + bf_hi(u3);
    }
    for (; e < end; ++e) {
        uint32 ue = hs[(size_t)colx[e] * 32 + l];
        a0 += bf_lo(ue); a1 += bf_hi(ue);
    }
    float d = dinv[node];
    float2 bb = *(const float2*)(b1 + 2 * l);
    float v0 = a0 * d + bb.x;
    float v1 = a1 * d + bb.y;
    float2 w;
    w.x = v0 > 0.f ? v0 : 0.f;
    w.y = v1 > 0.f ? v1 : 0.f;
    *(float2*)(h1 + (size_t)node * HID + 2 * l) = w;
}

// ---------------- Layer 2 GEMM: h2b(bf16) = (h1 @ W2) * dinv ----------------

__global__ __launch_bounds__(256) void gemm2_kernel(const float* __restrict__ h1,
                                                    const float* __restrict__ W2,
                                                    const float* __restrict__ dinv,
                                                    unsigned short* __restrict__ h2b, int M) {
    __shared__ float hsld[64][68];
    __shared__ float wls[64 * 40];
    int tid = threadIdx.x;
    int row0 = blockIdx.x * 64;

    int r = tid >> 2;
    int kb = (tid & 3) * 16;
    int grow = row0 + r; if (grow > M - 1) grow = M - 1;
    const float4* srcp = (const float4*)(h1 + (size_t)grow * HID + kb);
    *(float4*)&hsld[r][kb + 0] = srcp[0];
    *(float4*)&hsld[r][kb + 4] = srcp[1];
    *(float4*)&hsld[r][kb + 8] = srcp[2];
    *(float4*)&hsld[r][kb + 12] = srcp[3];
    for (int idx = tid; idx < HID * NC; idx += 256) wls[idx] = W2[idx];
    __syncthreads();

    for (int o = tid; o < 64 * NC; o += 256) {
        int rr = o / NC;
        int c = o - rr * NC;
        float s = 0.f;
#pragma unroll
        for (int k4 = 0; k4 < 16; ++k4) {
            float4 hv = *(float4*)&hsld[rr][k4 * 4];
            s += hv.x * wls[(k4 * 4 + 0) * NC + c];
            s += hv.y * wls[(k4 * 4 + 1) * NC + c];
            s += hv.z * wls[(k4 * 4 + 2) * NC + c];
            s += hv.w * wls[(k4 * 4 + 3) * NC + c];
        }
        int row = row0 + rr;
        if (row < M) h2b[(size_t)row * NC + c] = (unsigned short)f2bf(s * dinv[row]);
    }
}

// ---------------- agg2 + bias + log_softmax: half-wave per node ----------------

__global__ __launch_bounds__(256) void agg2_kernel(const uint32* __restrict__ h2b,
                                                   const int* __restrict__ rowptr,
                                                   const int* __restrict__ colx,
                                                   const float* __restrict__ dinv,
                                                   const float* __restrict__ b2,
                                                   float* __restrict__ out) {
    int node = (blockIdx.x * blockDim.x + threadIdx.x) >> 5;
    int l = threadIdx.x & 31;
    if (node >= NN) return;
    bool act = l < 20;  // 20 bf162 words cover 40 classes
    int beg = rowptr[node], end = rowptr[node + 1];
    float a0 = 0.f, a1 = 0.f;
    if (act) {
        uint32 u = h2b[(size_t)node * 20 + l];
        a0 = bf_lo(u); a1 = bf_hi(u);
    }
    int e = beg;
    for (; e + 3 < end; e += 4) {
        int c0 = colx[e], c1 = colx[e + 1], c2 = colx[e + 2], c3 = colx[e + 3];
        if (act) {
            uint32 u0 = h2b[(size_t)c0 * 20 + l];
            uint32 u1 = h2b[(size_t)c1 * 20 + l];
            uint32 u2 = h2b[(size_t)c2 * 20 + l];
            uint32 u3 = h2b[(size_t)c3 * 20 + l];
            a0 += bf_lo(u0) + bf_lo(u1) + bf_lo(u2) + bf_lo(u3);
            a1 += bf_hi(u0) + bf_hi(u1) + bf_hi(u2) + bf_hi(u3);
        }
    }
    for (; e < end; ++e) {
        if (act) {
            uint32 ue = h2b[(size_t)colx[e] * 20 + l];
            a0 += bf_lo(ue); a1 += bf_hi(ue);
        }
    }

    float d = dinv[node];
    float v0 = -INFINITY, v1 = -INFINITY;
    if (act) {
        float2 bb = *(const float2*)(b2 + 2 * l);
        v0 = a0 * d + bb.x;
        v1 = a1 * d + bb.y;
    }
    float m = fmaxf(v0, v1);
#pragma unroll
    for (int off = 16; off; off >>= 1) m = fmaxf(m, __shfl_xor(m, off));
    float s = act ? (expf(v0 - m) + expf(v1 - m)) : 0.f;
#pragma unroll
    for (int off = 16; off; off >>= 1) s += __shfl_xor(s, off);
    if (act) {
        float ls = logf(s);
        float2 w;
        w.x = v0 - m - ls;
        w.y = v1 - m - ls;
        *(float2*)(out + (size_t)node * NC + 2 * l) = w;
    }
}

// ---------------- launch ----------------

extern "C" void kernel_launch(void* const* d_in, const int* in_sizes, int n_in,
                              void* d_out, int out_size, void* d_ws, size_t ws_size,
                              hipStream_t stream) {
    const float* x  = (const float*)d_in[0];
    const int* ei   = (const int*)d_in[1];
    const float* W1 = (const float*)d_in[2];
    const float* b1 = (const float*)d_in[3];
    const float* W2 = (const float*)d_in[4];
    const float* b2 = (const float*)d_in[5];
    float* out = (float*)d_out;

    const int E = in_sizes[1] / 2;
    const int* src = ei;
    const int* dst = ei + E;

    char* p = (char*)d_ws;
    size_t off = 0;
    auto carve = [&](size_t bytes) {
        void* q = p + off;
        off = (off + bytes + 255) & ~(size_t)255;
        return q;
    };
    int* ghist    = (int*)carve((size_t)NBKT * 4);
    int* bbase    = (int*)carve((size_t)(NBKT + 1) * 4);
    int* gcursor  = (int*)carve((size_t)NBKT * 4);
    int* rowptr   = (int*)carve((size_t)(NN + 1) * 4);
    float* dinv   = (float*)carve((size_t)NN * 4);
    int* colx     = (int*)carve((size_t)E * 4);
    uint32* hs    = (uint32*)carve((size_t)NN * 32 * 4);        // bf16 [NN][64]
    unsigned short* h2b = (unsigned short*)carve((size_t)NN * NC * 2);  // bf16 [NN][40]
    float* h1     = (float*)carve((size_t)NN * HID * 4);
    int* packed   = (int*)h1;  // staging; dead before agg1 writes h1

    zero_kernel<<<(NBKT + 255) / 256, 256, 0, stream>>>(ghist, NBKT);
    bhist_kernel<<<256, 256, 0, stream>>>(dst, ghist, E);
    bscan_kernel<<<1, 512, 0, stream>>>(ghist, bbase, gcursor);
    bin_kernel<<<NBIN_BLOCKS, 512, 0, stream>>>(src, dst, gcursor, packed, E);
    csr_bucket_kernel<<<NBKT, 256, 0, stream>>>(packed, bbase, rowptr, colx, dinv, E);
    gemm1_kernel<<<(NN + 63) / 64, 256, 0, stream>>>(x, W1, dinv, hs, NN);
    agg1_kernel<<<(NN * 32 + 255) / 256, 256, 0, stream>>>(hs, rowptr, colx, dinv, b1, h1);
    gemm2_kernel<<<(NN + 63) / 64, 256, 0, stream>>>(h1, W2, dinv, h2b, NN);
    agg2_kernel<<<(NN * 32 + 255) / 256, 256, 0, stream>>>((const uint32*)h2b, rowptr, colx, dinv, b2, out);
}

// Round 5
// 351.904 us; speedup vs baseline: 3.0396x; 1.2141x over previous
//
#include <hip/hip_runtime.h>
#include <hip/hip_bf16.h>
#include <cmath>

#define NN 100000
#define IND 512
#define HID 64
#define NC  40
#define BWN 256                      // nodes per bucket
#define NBKT ((NN + BWN - 1) / BWN)  // 391
#define NBIN_BLOCKS 100

typedef unsigned int uint32;
typedef unsigned short ushort;
using short8 = __attribute__((ext_vector_type(8))) short;
using f32x4  = __attribute__((ext_vector_type(4))) float;

__device__ inline float bf_lo(uint32 u) { return __uint_as_float(u << 16); }
__device__ inline float bf_hi(uint32 u) { return __uint_as_float(u & 0xFFFF0000u); }
__device__ inline uint32 f2bf(float f) {
    uint32 u = __float_as_uint(f);
    return (u + 0x7FFFu + ((u >> 16) & 1u)) >> 16;  // RNE
}
__device__ inline uint32 pack2bf(float a, float b) { return f2bf(a) | (f2bf(b) << 16); }

// ---------------- CSR build: two-level bucket sort ----------------

__global__ __launch_bounds__(256) void zero_kernel(int* __restrict__ ghist, int n) {
    int i = blockIdx.x * blockDim.x + threadIdx.x;
    if (i < n) ghist[i] = 0;
}

__global__ __launch_bounds__(256) void bhist_kernel(const int* __restrict__ dst,
                                                    int* __restrict__ ghist, int E) {
    __shared__ int hist[NBKT];
    int t = threadIdx.x;
    for (int i = t; i < NBKT; i += 256) hist[i] = 0;
    __syncthreads();
    for (int e = blockIdx.x * 256 + t; e < E; e += gridDim.x * 256)
        atomicAdd(&hist[dst[e] >> 8], 1);
    __syncthreads();
    for (int i = t; i < NBKT; i += 256)
        if (hist[i]) atomicAdd(&ghist[i], hist[i]);
}

__global__ __launch_bounds__(512) void bscan_kernel(const int* __restrict__ ghist,
                                                    int* __restrict__ bbase,
                                                    int* __restrict__ gcursor) {
    __shared__ int sh[512];
    int t = threadIdx.x;
    int v = (t < NBKT) ? ghist[t] : 0;
    sh[t] = v;
    __syncthreads();
    for (int off = 1; off < 512; off <<= 1) {
        int u = (t >= off) ? sh[t - off] : 0;
        __syncthreads();
        sh[t] += u;
        __syncthreads();
    }
    int ex = sh[t] - v;
    if (t < NBKT) { bbase[t] = ex; gcursor[t] = ex; }
    if (t == NBKT - 1) bbase[NBKT] = ex + v;
}

__global__ __launch_bounds__(512) void bin_kernel(const int* __restrict__ src,
                                                  const int* __restrict__ dst,
                                                  int* __restrict__ gcursor,
                                                  int* __restrict__ packed, int E) {
    __shared__ int hist[NBKT], base[NBKT], cur[NBKT];
    int b = blockIdx.x, t = threadIdx.x;
    int epb = (E + gridDim.x - 1) / gridDim.x;
    int lo = b * epb;
    int hi = lo + epb; if (hi > E) hi = E;
    for (int i = t; i < NBKT; i += 512) { hist[i] = 0; cur[i] = 0; }
    __syncthreads();
    for (int e = lo + t; e < hi; e += 512) atomicAdd(&hist[dst[e] >> 8], 1);
    __syncthreads();
    for (int i = t; i < NBKT; i += 512)
        if (hist[i]) base[i] = atomicAdd(&gcursor[i], hist[i]);
    __syncthreads();
    for (int e = lo + t; e < hi; e += 512) {
        int d = dst[e], s = src[e];
        int bk = d >> 8;
        int pos = base[bk] + atomicAdd(&cur[bk], 1);
        packed[pos] = ((d & 255) << 17) | s;
    }
}

__global__ __launch_bounds__(256) void csr_bucket_kernel(const int* __restrict__ packed,
                                                         const int* __restrict__ bbase,
                                                         int* __restrict__ rowptr,
                                                         int* __restrict__ colx,
                                                         float* __restrict__ dinv, int E) {
    __shared__ int hist[BWN], pfx[BWN], cur[BWN];
    int b = blockIdx.x, t = threadIdx.x;
    int nlo = b * BWN;
    int ncnt = NN - nlo; if (ncnt > BWN) ncnt = BWN;
    int ebeg = bbase[b], eend = bbase[b + 1];
    hist[t] = 0;
    __syncthreads();
    for (int e = ebeg + t; e < eend; e += 256) atomicAdd(&hist[packed[e] >> 17], 1);
    __syncthreads();
    int h = hist[t];
    pfx[t] = h;
    __syncthreads();
    for (int off = 1; off < 256; off <<= 1) {
        int u = (t >= off) ? pfx[t - off] : 0;
        __syncthreads();
        pfx[t] += u;
        __syncthreads();
    }
    int excl = pfx[t] - h;
    cur[t] = excl;
    int g = nlo + t;
    if (t < ncnt) {
        rowptr[g] = ebeg + excl;
        dinv[g] = rsqrtf((float)(h + 1));  // +1 self-loop
    }
    if (b == 0 && t == 0) rowptr[NN] = E;
    __syncthreads();
    for (int e = ebeg + t; e < eend; e += 256) {
        int p = packed[e];
        int dl = p >> 17;
        int s = p & 0x1FFFF;
        int pos = ebeg + atomicAdd(&cur[dl], 1);
        colx[pos] = s;
    }
}

// ---------------- W1 transpose + bf16 convert: W1T[n][k] = bf16(W1[k][n]) ----------------

__global__ __launch_bounds__(256) void w1t_kernel(const float* __restrict__ W1,
                                                  ushort* __restrict__ w1t) {
    int id = blockIdx.x * blockDim.x + threadIdx.x;  // 0 .. 512*64-1
    if (id >= IND * HID) return;
    int n = id & 63, k = id >> 6;
    w1t[(size_t)n * IND + k] = (ushort)f2bf(W1[(size_t)k * HID + n]);
}

// ---------------- Layer 1 GEMM (MFMA bf16): hs = bf16((x @ W1) * dinv[row]) ----------------
// 4 waves, block tile 64x64, BK=64. LDS [row][k] bf16 with XOR swizzle (row&7)<<4.

__global__ __launch_bounds__(256) void gemm1_mfma(const float* __restrict__ x,
                                                  const ushort* __restrict__ w1t,
                                                  const float* __restrict__ dinv,
                                                  ushort* __restrict__ hs, int M) {
    __shared__ ushort As[64 * 64];  // 8 KB
    __shared__ ushort Bs[64 * 64];  // 8 KB
    char* Ab = (char*)As;
    char* Bb = (char*)Bs;

    int t = threadIdx.x;
    int row0 = blockIdx.x * 64;

    int srow = t >> 2;        // staging row / b-col, 0..63
    int klane = t & 3;        // 0..3
    int grow = row0 + srow; if (grow > M - 1) grow = M - 1;
    const float* xrow = x + (size_t)grow * IND;
    const char* wrow = (const char*)(w1t + (size_t)srow * IND);
    int swrow = srow * 128;
    int swx = (srow & 7) << 4;

    int l = t & 63;
    int w = t >> 6;
    int lr = l & 15;
    int lk = (l >> 4) * 16;   // byte offset of 8-bf16 chunk within 64B k-step
    int arow_b = (w * 16 + lr) * 128;
    int aswz = ((w * 16 + lr) & 7) << 4;

    f32x4 acc[4] = {};

    for (int k0 = 0; k0 < IND; k0 += 64) {
#pragma unroll
        for (int i = 0; i < 4; ++i) {
            float4 v = *(const float4*)(xrow + k0 + i * 16 + klane * 4);
            uint2 pkd;
            pkd.x = pack2bf(v.x, v.y);
            pkd.y = pack2bf(v.z, v.w);
            int kb = i * 32 + klane * 8;
            *(uint2*)(Ab + swrow + (kb ^ swx)) = pkd;
            uint2 wv = *(const uint2*)(wrow + k0 * 2 + kb);
            *(uint2*)(Bb + swrow + (kb ^ swx)) = wv;
        }
        __syncthreads();

        short8 a0 = *(const short8*)(Ab + arow_b + ((0 + lk) ^ aswz));
        short8 a1 = *(const short8*)(Ab + arow_b + ((64 + lk) ^ aswz));
#pragma unroll
        for (int ns = 0; ns < 4; ++ns) {
            int brow = ns * 16 + lr;
            int bswz = (brow & 7) << 4;
            short8 b0 = *(const short8*)(Bb + brow * 128 + ((0 + lk) ^ bswz));
            short8 b1 = *(const short8*)(Bb + brow * 128 + ((64 + lk) ^ bswz));
            acc[ns] = __builtin_amdgcn_mfma_f32_16x16x32_bf16(a0, b0, acc[ns], 0, 0, 0);
            acc[ns] = __builtin_amdgcn_mfma_f32_16x16x32_bf16(a1, b1, acc[ns], 0, 0, 0);
        }
        __syncthreads();
    }

    // epilogue: C/D layout col=l&15, row=(l>>4)*4+j
    int rbase = row0 + w * 16 + (l >> 4) * 4;
    float dv[4];
#pragma unroll
    for (int j = 0; j < 4; ++j) dv[j] = (rbase + j < M) ? dinv[rbase + j] : 0.f;
#pragma unroll
    for (int ns = 0; ns < 4; ++ns) {
        int col = ns * 16 + lr;
#pragma unroll
        for (int j = 0; j < 4; ++j) {
            int row = rbase + j;
            if (row < M) hs[(size_t)row * HID + col] = (ushort)f2bf(acc[ns][j] * dv[j]);
        }
    }
}

// ---------------- agg1: half-wave per node, bf16 gather, f32 accum ----------------

__global__ __launch_bounds__(256) void agg1_kernel(const uint32* __restrict__ hs,
                                                   const int* __restrict__ rowptr,
                                                   const int* __restrict__ colx,
                                                   const float* __restrict__ dinv,
                                                   const float* __restrict__ b1,
                                                   float* __restrict__ h1) {
    int node = (blockIdx.x * blockDim.x + threadIdx.x) >> 5;
    int l = threadIdx.x & 31;
    if (node >= NN) return;
    int beg = rowptr[node], end = rowptr[node + 1];
    uint32 u = hs[(size_t)node * 32 + l];  // self (already dinv-scaled)
    float a0 = bf_lo(u), a1 = bf_hi(u);
    int e = beg;
    for (; e + 3 < end; e += 4) {
        int c0 = colx[e], c1 = colx[e + 1], c2 = colx[e + 2], c3 = colx[e + 3];
        uint32 u0 = hs[(size_t)c0 * 32 + l];
        uint32 u1 = hs[(size_t)c1 * 32 + l];
        uint32 u2 = hs[(size_t)c2 * 32 + l];
        uint32 u3 = hs[(size_t)c3 * 32 + l];
        a0 += bf_lo(u0) + bf_lo(u1) + bf_lo(u2) + bf_lo(u3);
        a1 += bf_hi(u0) + bf_hi(u1) + bf_hi(u2) + bf_hi(u3);
    }
    for (; e < end; ++e) {
        uint32 ue = hs[(size_t)colx[e] * 32 + l];
        a0 += bf_lo(ue); a1 += bf_hi(ue);
    }
    float d = dinv[node];
    float2 bb = *(const float2*)(b1 + 2 * l);
    float v0 = a0 * d + bb.x;
    float v1 = a1 * d + bb.y;
    float2 w;
    w.x = v0 > 0.f ? v0 : 0.f;
    w.y = v1 > 0.f ? v1 : 0.f;
    *(float2*)(h1 + (size_t)node * HID + 2 * l) = w;
}

// ---------------- Layer 2 GEMM: h2b(bf16) = (h1 @ W2) * dinv ----------------

__global__ __launch_bounds__(256) void gemm2_kernel(const float* __restrict__ h1,
                                                    const float* __restrict__ W2,
                                                    const float* __restrict__ dinv,
                                                    ushort* __restrict__ h2b, int M) {
    __shared__ float hsld[64][68];
    __shared__ float wls[64 * 40];
    int tid = threadIdx.x;
    int row0 = blockIdx.x * 64;

    int r = tid >> 2;
    int kb = (tid & 3) * 16;
    int grow = row0 + r; if (grow > M - 1) grow = M - 1;
    const float4* srcp = (const float4*)(h1 + (size_t)grow * HID + kb);
    *(float4*)&hsld[r][kb + 0] = srcp[0];
    *(float4*)&hsld[r][kb + 4] = srcp[1];
    *(float4*)&hsld[r][kb + 8] = srcp[2];
    *(float4*)&hsld[r][kb + 12] = srcp[3];
    for (int idx = tid; idx < HID * NC; idx += 256) wls[idx] = W2[idx];
    __syncthreads();

    for (int o = tid; o < 64 * NC; o += 256) {
        int rr = o / NC;
        int c = o - rr * NC;
        float s = 0.f;
#pragma unroll
        for (int k4 = 0; k4 < 16; ++k4) {
            float4 hv = *(float4*)&hsld[rr][k4 * 4];
            s += hv.x * wls[(k4 * 4 + 0) * NC + c];
            s += hv.y * wls[(k4 * 4 + 1) * NC + c];
            s += hv.z * wls[(k4 * 4 + 2) * NC + c];
            s += hv.w * wls[(k4 * 4 + 3) * NC + c];
        }
        int row = row0 + rr;
        if (row < M) h2b[(size_t)row * NC + c] = (ushort)f2bf(s * dinv[row]);
    }
}

// ---------------- agg2 + bias + log_softmax: half-wave per node ----------------

__global__ __launch_bounds__(256) void agg2_kernel(const uint32* __restrict__ h2b,
                                                   const int* __restrict__ rowptr,
                                                   const int* __restrict__ colx,
                                                   const float* __restrict__ dinv,
                                                   const float* __restrict__ b2,
                                                   float* __restrict__ out) {
    int node = (blockIdx.x * blockDim.x + threadIdx.x) >> 5;
    int l = threadIdx.x & 31;
    if (node >= NN) return;
    bool act = l < 20;  // 20 bf162 words cover 40 classes
    int beg = rowptr[node], end = rowptr[node + 1];
    float a0 = 0.f, a1 = 0.f;
    if (act) {
        uint32 u = h2b[(size_t)node * 20 + l];
        a0 = bf_lo(u); a1 = bf_hi(u);
    }
    int e = beg;
    for (; e + 3 < end; e += 4) {
        int c0 = colx[e], c1 = colx[e + 1], c2 = colx[e + 2], c3 = colx[e + 3];
        if (act) {
            uint32 u0 = h2b[(size_t)c0 * 20 + l];
            uint32 u1 = h2b[(size_t)c1 * 20 + l];
            uint32 u2 = h2b[(size_t)c2 * 20 + l];
            uint32 u3 = h2b[(size_t)c3 * 20 + l];
            a0 += bf_lo(u0) + bf_lo(u1) + bf_lo(u2) + bf_lo(u3);
            a1 += bf_hi(u0) + bf_hi(u1) + bf_hi(u2) + bf_hi(u3);
        }
    }
    for (; e < end; ++e) {
        if (act) {
            uint32 ue = h2b[(size_t)colx[e] * 20 + l];
            a0 += bf_lo(ue); a1 += bf_hi(ue);
        }
    }

    float d = dinv[node];
    float v0 = -INFINITY, v1 = -INFINITY;
    if (act) {
        float2 bb = *(const float2*)(b2 + 2 * l);
        v0 = a0 * d + bb.x;
        v1 = a1 * d + bb.y;
    }
    float m = fmaxf(v0, v1);
#pragma unroll
    for (int off = 16; off; off >>= 1) m = fmaxf(m, __shfl_xor(m, off));
    float s = act ? (expf(v0 - m) + expf(v1 - m)) : 0.f;
#pragma unroll
    for (int off = 16; off; off >>= 1) s += __shfl_xor(s, off);
    if (act) {
        float ls = logf(s);
        float2 w;
        w.x = v0 - m - ls;
        w.y = v1 - m - ls;
        *(float2*)(out + (size_t)node * NC + 2 * l) = w;
    }
}

// ---------------- launch ----------------

extern "C" void kernel_launch(void* const* d_in, const int* in_sizes, int n_in,
                              void* d_out, int out_size, void* d_ws, size_t ws_size,
                              hipStream_t stream) {
    const float* x  = (const float*)d_in[0];
    const int* ei   = (const int*)d_in[1];
    const float* W1 = (const float*)d_in[2];
    const float* b1 = (const float*)d_in[3];
    const float* W2 = (const float*)d_in[4];
    const float* b2 = (const float*)d_in[5];
    float* out = (float*)d_out;

    const int E = in_sizes[1] / 2;
    const int* src = ei;
    const int* dst = ei + E;

    char* p = (char*)d_ws;
    size_t off = 0;
    auto carve = [&](size_t bytes) {
        void* q = p + off;
        off = (off + bytes + 255) & ~(size_t)255;
        return q;
    };
    int* ghist    = (int*)carve((size_t)NBKT * 4);
    int* bbase    = (int*)carve((size_t)(NBKT + 1) * 4);
    int* gcursor  = (int*)carve((size_t)NBKT * 4);
    int* rowptr   = (int*)carve((size_t)(NN + 1) * 4);
    float* dinv   = (float*)carve((size_t)NN * 4);
    int* colx     = (int*)carve((size_t)E * 4);
    ushort* w1t   = (ushort*)carve((size_t)IND * HID * 2);      // bf16 W1^T [64][512]
    ushort* hs    = (ushort*)carve((size_t)NN * HID * 2);       // bf16 [NN][64]
    ushort* h2b   = (ushort*)carve((size_t)NN * NC * 2);        // bf16 [NN][40]
    float* h1     = (float*)carve((size_t)NN * HID * 4);
    int* packed   = (int*)h1;  // staging; dead before agg1 writes h1

    zero_kernel<<<(NBKT + 255) / 256, 256, 0, stream>>>(ghist, NBKT);
    bhist_kernel<<<256, 256, 0, stream>>>(dst, ghist, E);
    bscan_kernel<<<1, 512, 0, stream>>>(ghist, bbase, gcursor);
    bin_kernel<<<NBIN_BLOCKS, 512, 0, stream>>>(src, dst, gcursor, packed, E);
    csr_bucket_kernel<<<NBKT, 256, 0, stream>>>(packed, bbase, rowptr, colx, dinv, E);
    w1t_kernel<<<(IND * HID + 255) / 256, 256, 0, stream>>>(W1, w1t);
    gemm1_mfma<<<(NN + 63) / 64, 256, 0, stream>>>(x, w1t, dinv, hs, NN);
    agg1_kernel<<<(NN * 32 + 255) / 256, 256, 0, stream>>>((const uint32*)hs, rowptr, colx, dinv, b1, h1);
    gemm2_kernel<<<(NN + 63) / 64, 256, 0, stream>>>(h1, W2, dinv, h2b, NN);
    agg2_kernel<<<(NN * 32 + 255) / 256, 256, 0, stream>>>((const uint32*)h2b, rowptr, colx, dinv, b2, out);
}

// Round 6
// 337.240 us; speedup vs baseline: 3.1718x; 1.0435x over previous
//
#include <hip/hip_runtime.h>
#include <hip/hip_bf16.h>
#include <cmath>

#define NN 100000
#define IND 512
#define HID 64
#define NC  40
#define BWN 256                      // nodes per bucket
#define NBKT ((NN + BWN - 1) / BWN)  // 391
#define NBIN_BLOCKS 100

typedef unsigned int uint32;
typedef unsigned short ushort;
using short8 = __attribute__((ext_vector_type(8))) short;
using f32x4  = __attribute__((ext_vector_type(4))) float;

__device__ inline float bf_lo(uint32 u) { return __uint_as_float(u << 16); }
__device__ inline float bf_hi(uint32 u) { return __uint_as_float(u & 0xFFFF0000u); }
__device__ inline uint32 f2bf(float f) {
    uint32 u = __float_as_uint(f);
    return (u + 0x7FFFu + ((u >> 16) & 1u)) >> 16;  // RNE
}
__device__ inline uint32 pack2bf(float a, float b) { return f2bf(a) | (f2bf(b) << 16); }

// ---------------- CSR build: two-level bucket sort ----------------

__global__ __launch_bounds__(256) void zero_kernel(int* __restrict__ ghist, int n) {
    int i = blockIdx.x * blockDim.x + threadIdx.x;
    if (i < n) ghist[i] = 0;
}

__global__ __launch_bounds__(256) void bhist_kernel(const int* __restrict__ dst,
                                                    int* __restrict__ ghist, int E) {
    __shared__ int hist[NBKT];
    int t = threadIdx.x;
    for (int i = t; i < NBKT; i += 256) hist[i] = 0;
    __syncthreads();
    for (int e = blockIdx.x * 256 + t; e < E; e += gridDim.x * 256)
        atomicAdd(&hist[dst[e] >> 8], 1);
    __syncthreads();
    for (int i = t; i < NBKT; i += 256)
        if (hist[i]) atomicAdd(&ghist[i], hist[i]);
}

__global__ __launch_bounds__(512) void bscan_kernel(const int* __restrict__ ghist,
                                                    int* __restrict__ bbase,
                                                    int* __restrict__ gcursor) {
    __shared__ int sh[512];
    int t = threadIdx.x;
    int v = (t < NBKT) ? ghist[t] : 0;
    sh[t] = v;
    __syncthreads();
    for (int off = 1; off < 512; off <<= 1) {
        int u = (t >= off) ? sh[t - off] : 0;
        __syncthreads();
        sh[t] += u;
        __syncthreads();
    }
    int ex = sh[t] - v;
    if (t < NBKT) { bbase[t] = ex; gcursor[t] = ex; }
    if (t == NBKT - 1) bbase[NBKT] = ex + v;
}

__global__ __launch_bounds__(512) void bin_kernel(const int* __restrict__ src,
                                                  const int* __restrict__ dst,
                                                  int* __restrict__ gcursor,
                                                  int* __restrict__ packed, int E) {
    __shared__ int hist[NBKT], base[NBKT], cur[NBKT];
    int b = blockIdx.x, t = threadIdx.x;
    int epb = (E + gridDim.x - 1) / gridDim.x;
    int lo = b * epb;
    int hi = lo + epb; if (hi > E) hi = E;
    for (int i = t; i < NBKT; i += 512) { hist[i] = 0; cur[i] = 0; }
    __syncthreads();
    for (int e = lo + t; e < hi; e += 512) atomicAdd(&hist[dst[e] >> 8], 1);
    __syncthreads();
    for (int i = t; i < NBKT; i += 512)
        if (hist[i]) base[i] = atomicAdd(&gcursor[i], hist[i]);
    __syncthreads();
    for (int e = lo + t; e < hi; e += 512) {
        int d = dst[e], s = src[e];
        int bk = d >> 8;
        int pos = base[bk] + atomicAdd(&cur[bk], 1);
        packed[pos] = ((d & 255) << 17) | s;
    }
}

__global__ __launch_bounds__(256) void csr_bucket_kernel(const int* __restrict__ packed,
                                                         const int* __restrict__ bbase,
                                                         int* __restrict__ rowptr,
                                                         int* __restrict__ colx,
                                                         float* __restrict__ dinv, int E) {
    __shared__ int hist[BWN], pfx[BWN], cur[BWN];
    int b = blockIdx.x, t = threadIdx.x;
    int nlo = b * BWN;
    int ncnt = NN - nlo; if (ncnt > BWN) ncnt = BWN;
    int ebeg = bbase[b], eend = bbase[b + 1];
    hist[t] = 0;
    __syncthreads();
    for (int e = ebeg + t; e < eend; e += 256) atomicAdd(&hist[packed[e] >> 17], 1);
    __syncthreads();
    int h = hist[t];
    pfx[t] = h;
    __syncthreads();
    for (int off = 1; off < 256; off <<= 1) {
        int u = (t >= off) ? pfx[t - off] : 0;
        __syncthreads();
        pfx[t] += u;
        __syncthreads();
    }
    int excl = pfx[t] - h;
    cur[t] = excl;
    int g = nlo + t;
    if (t < ncnt) {
        rowptr[g] = ebeg + excl;
        dinv[g] = rsqrtf((float)(h + 1));  // +1 self-loop
    }
    if (b == 0 && t == 0) rowptr[NN] = E;
    __syncthreads();
    for (int e = ebeg + t; e < eend; e += 256) {
        int p = packed[e];
        int dl = p >> 17;
        int s = p & 0x1FFFF;
        int pos = ebeg + atomicAdd(&cur[dl], 1);
        colx[pos] = s;
    }
}

// ---------------- W1 transpose + bf16 convert: W1T[n][k] = bf16(W1[k][n]) ----------------

__global__ __launch_bounds__(256) void w1t_kernel(const float* __restrict__ W1,
                                                  ushort* __restrict__ w1t) {
    int id = blockIdx.x * blockDim.x + threadIdx.x;  // 0 .. 512*64-1
    if (id >= IND * HID) return;
    int n = id & 63, k = id >> 6;
    w1t[(size_t)n * IND + k] = (ushort)f2bf(W1[(size_t)k * HID + n]);
}

// ---------------- Layer 1 GEMM (MFMA bf16): hs = bf16((x @ W1) * dinv[row]) ----------------
// 4 waves, block tile 64x64, BK=64. LDS [row][k] bf16 with XOR swizzle (row&7)<<4.

__global__ __launch_bounds__(256) void gemm1_mfma(const float* __restrict__ x,
                                                  const ushort* __restrict__ w1t,
                                                  const float* __restrict__ dinv,
                                                  ushort* __restrict__ hs, int M) {
    __shared__ ushort As[64 * 64];  // 8 KB
    __shared__ ushort Bs[64 * 64];  // 8 KB
    char* Ab = (char*)As;
    char* Bb = (char*)Bs;

    int t = threadIdx.x;
    int row0 = blockIdx.x * 64;

    int srow = t >> 2;        // staging row / b-col, 0..63
    int klane = t & 3;        // 0..3
    int grow = row0 + srow; if (grow > M - 1) grow = M - 1;
    const float* xrow = x + (size_t)grow * IND;
    const char* wrow = (const char*)(w1t + (size_t)srow * IND);
    int swrow = srow * 128;
    int swx = (srow & 7) << 4;

    int l = t & 63;
    int w = t >> 6;
    int lr = l & 15;
    int lk = (l >> 4) * 16;   // byte offset of 8-bf16 chunk within 64B k-step
    int arow_b = (w * 16 + lr) * 128;
    int aswz = ((w * 16 + lr) & 7) << 4;

    f32x4 acc[4] = {};

    for (int k0 = 0; k0 < IND; k0 += 64) {
#pragma unroll
        for (int i = 0; i < 4; ++i) {
            float4 v = *(const float4*)(xrow + k0 + i * 16 + klane * 4);
            uint2 pkd;
            pkd.x = pack2bf(v.x, v.y);
            pkd.y = pack2bf(v.z, v.w);
            int kb = i * 32 + klane * 8;
            *(uint2*)(Ab + swrow + (kb ^ swx)) = pkd;
            uint2 wv = *(const uint2*)(wrow + k0 * 2 + kb);
            *(uint2*)(Bb + swrow + (kb ^ swx)) = wv;
        }
        __syncthreads();

        short8 a0 = *(const short8*)(Ab + arow_b + ((0 + lk) ^ aswz));
        short8 a1 = *(const short8*)(Ab + arow_b + ((64 + lk) ^ aswz));
#pragma unroll
        for (int ns = 0; ns < 4; ++ns) {
            int brow = ns * 16 + lr;
            int bswz = (brow & 7) << 4;
            short8 b0 = *(const short8*)(Bb + brow * 128 + ((0 + lk) ^ bswz));
            short8 b1 = *(const short8*)(Bb + brow * 128 + ((64 + lk) ^ bswz));
            acc[ns] = __builtin_amdgcn_mfma_f32_16x16x32_bf16(a0, b0, acc[ns], 0, 0, 0);
            acc[ns] = __builtin_amdgcn_mfma_f32_16x16x32_bf16(a1, b1, acc[ns], 0, 0, 0);
        }
        __syncthreads();
    }

    // epilogue: C/D layout col=l&15, row=(l>>4)*4+j
    int rbase = row0 + w * 16 + (l >> 4) * 4;
    float dv[4];
#pragma unroll
    for (int j = 0; j < 4; ++j) dv[j] = (rbase + j < M) ? dinv[rbase + j] : 0.f;
#pragma unroll
    for (int ns = 0; ns < 4; ++ns) {
        int col = ns * 16 + lr;
#pragma unroll
        for (int j = 0; j < 4; ++j) {
            int row = rbase + j;
            if (row < M) hs[(size_t)row * HID + col] = (ushort)f2bf(acc[ns][j] * dv[j]);
        }
    }
}

// ---------------- agg1: half-wave per node, bf16 gather, f32 accum, bf16 h1 out ----------------

__global__ __launch_bounds__(256) void agg1_kernel(const uint32* __restrict__ hs,
                                                   const int* __restrict__ rowptr,
                                                   const int* __restrict__ colx,
                                                   const float* __restrict__ dinv,
                                                   const float* __restrict__ b1,
                                                   uint32* __restrict__ h1) {
    int node = (blockIdx.x * blockDim.x + threadIdx.x) >> 5;
    int l = threadIdx.x & 31;
    if (node >= NN) return;
    int beg = rowptr[node], end = rowptr[node + 1];
    uint32 u = hs[(size_t)node * 32 + l];  // self (already dinv-scaled)
    float a0 = bf_lo(u), a1 = bf_hi(u);
    int e = beg;
    int n8 = beg + ((end - beg) & ~7);
    for (; e < n8; e += 8) {
        int c[8];
#pragma unroll
        for (int j = 0; j < 8; ++j) c[j] = colx[e + j];
        uint32 uu[8];
#pragma unroll
        for (int j = 0; j < 8; ++j) uu[j] = hs[(size_t)c[j] * 32 + l];
#pragma unroll
        for (int j = 0; j < 8; ++j) { a0 += bf_lo(uu[j]); a1 += bf_hi(uu[j]); }
    }
    for (; e < end; ++e) {
        uint32 ue = hs[(size_t)colx[e] * 32 + l];
        a0 += bf_lo(ue); a1 += bf_hi(ue);
    }
    float d = dinv[node];
    float2 bb = *(const float2*)(b1 + 2 * l);
    float v0 = a0 * d + bb.x;
    float v1 = a1 * d + bb.y;
    v0 = v0 > 0.f ? v0 : 0.f;
    v1 = v1 > 0.f ? v1 : 0.f;
    __builtin_nontemporal_store(pack2bf(v0, v1), &h1[(size_t)node * 32 + l]);
}

// ---------------- Layer 2 GEMM: h2b(bf16) = (h1(bf16) @ W2) * dinv ----------------

__global__ __launch_bounds__(256) void gemm2_kernel(const uint32* __restrict__ h1,
                                                    const float* __restrict__ W2,
                                                    const float* __restrict__ dinv,
                                                    ushort* __restrict__ h2b, int M) {
    __shared__ float hsld[64][68];
    __shared__ float wls[64 * 40];
    int tid = threadIdx.x;
    int row0 = blockIdx.x * 64;

    int r = tid >> 2;          // tile row 0..63
    int q = tid & 3;           // quarter: 16 feats each
    int grow = row0 + r; if (grow > M - 1) grow = M - 1;
    const uint4* srcp = (const uint4*)(h1 + (size_t)grow * 32);
    uint4 q0 = srcp[q * 2];
    uint4 q1 = srcp[q * 2 + 1];
    uint32 wv[8] = {q0.x, q0.y, q0.z, q0.w, q1.x, q1.y, q1.z, q1.w};
#pragma unroll
    for (int jw = 0; jw < 8; ++jw) {
        hsld[r][q * 16 + 2 * jw]     = bf_lo(wv[jw]);
        hsld[r][q * 16 + 2 * jw + 1] = bf_hi(wv[jw]);
    }
    for (int idx = tid; idx < HID * NC; idx += 256) wls[idx] = W2[idx];
    __syncthreads();

    for (int o = tid; o < 64 * NC; o += 256) {
        int rr = o / NC;
        int c = o - rr * NC;
        float s = 0.f;
#pragma unroll
        for (int k4 = 0; k4 < 16; ++k4) {
            float4 hv = *(float4*)&hsld[rr][k4 * 4];
            s += hv.x * wls[(k4 * 4 + 0) * NC + c];
            s += hv.y * wls[(k4 * 4 + 1) * NC + c];
            s += hv.z * wls[(k4 * 4 + 2) * NC + c];
            s += hv.w * wls[(k4 * 4 + 3) * NC + c];
        }
        int row = row0 + rr;
        if (row < M) h2b[(size_t)row * NC + c] = (ushort)f2bf(s * dinv[row]);
    }
}

// ---------------- agg2 + bias + log_softmax: half-wave per node ----------------

__global__ __launch_bounds__(256) void agg2_kernel(const uint32* __restrict__ h2b,
                                                   const int* __restrict__ rowptr,
                                                   const int* __restrict__ colx,
                                                   const float* __restrict__ dinv,
                                                   const float* __restrict__ b2,
                                                   float* __restrict__ out) {
    int node = (blockIdx.x * blockDim.x + threadIdx.x) >> 5;
    int l = threadIdx.x & 31;
    if (node >= NN) return;
    bool act = l < 20;  // 20 bf162 words cover 40 classes
    int beg = rowptr[node], end = rowptr[node + 1];
    float a0 = 0.f, a1 = 0.f;
    if (act) {
        uint32 u = h2b[(size_t)node * 20 + l];
        a0 = bf_lo(u); a1 = bf_hi(u);
    }
    int e = beg;
    int n8 = beg + ((end - beg) & ~7);
    for (; e < n8; e += 8) {
        int c[8];
#pragma unroll
        for (int j = 0; j < 8; ++j) c[j] = colx[e + j];
        if (act) {
            uint32 uu[8];
#pragma unroll
            for (int j = 0; j < 8; ++j) uu[j] = h2b[(size_t)c[j] * 20 + l];
#pragma unroll
            for (int j = 0; j < 8; ++j) { a0 += bf_lo(uu[j]); a1 += bf_hi(uu[j]); }
        }
    }
    for (; e < end; ++e) {
        if (act) {
            uint32 ue = h2b[(size_t)colx[e] * 20 + l];
            a0 += bf_lo(ue); a1 += bf_hi(ue);
        }
    }

    float d = dinv[node];
    float v0 = -INFINITY, v1 = -INFINITY;
    if (act) {
        float2 bb = *(const float2*)(b2 + 2 * l);
        v0 = a0 * d + bb.x;
        v1 = a1 * d + bb.y;
    }
    float m = fmaxf(v0, v1);
#pragma unroll
    for (int off = 16; off; off >>= 1) m = fmaxf(m, __shfl_xor(m, off));
    float s = act ? (expf(v0 - m) + expf(v1 - m)) : 0.f;
#pragma unroll
    for (int off = 16; off; off >>= 1) s += __shfl_xor(s, off);
    if (act) {
        float ls = logf(s);
        __builtin_nontemporal_store(v0 - m - ls, &out[(size_t)node * NC + 2 * l]);
        __builtin_nontemporal_store(v1 - m - ls, &out[(size_t)node * NC + 2 * l + 1]);
    }
}

// ---------------- launch ----------------

extern "C" void kernel_launch(void* const* d_in, const int* in_sizes, int n_in,
                              void* d_out, int out_size, void* d_ws, size_t ws_size,
                              hipStream_t stream) {
    const float* x  = (const float*)d_in[0];
    const int* ei   = (const int*)d_in[1];
    const float* W1 = (const float*)d_in[2];
    const float* b1 = (const float*)d_in[3];
    const float* W2 = (const float*)d_in[4];
    const float* b2 = (const float*)d_in[5];
    float* out = (float*)d_out;

    const int E = in_sizes[1] / 2;
    const int* src = ei;
    const int* dst = ei + E;

    char* p = (char*)d_ws;
    size_t off = 0;
    auto carve = [&](size_t bytes) {
        void* q = p + off;
        off = (off + bytes + 255) & ~(size_t)255;
        return q;
    };
    int* ghist    = (int*)carve((size_t)NBKT * 4);
    int* bbase    = (int*)carve((size_t)(NBKT + 1) * 4);
    int* gcursor  = (int*)carve((size_t)NBKT * 4);
    int* rowptr   = (int*)carve((size_t)(NN + 1) * 4);
    float* dinv   = (float*)carve((size_t)NN * 4);
    int* colx     = (int*)carve((size_t)E * 4);
    ushort* w1t   = (ushort*)carve((size_t)IND * HID * 2);      // bf16 W1^T [64][512]
    ushort* hs    = (ushort*)carve((size_t)NN * HID * 2);       // bf16 [NN][64]
    ushort* h2b   = (ushort*)carve((size_t)NN * NC * 2);        // bf16 [NN][40]
    uint32* h1    = (uint32*)carve((size_t)NN * 32 * 4);        // bf16 pairs [NN][32]
    int* packed   = (int*)carve((size_t)E * 4);                 // bin staging

    zero_kernel<<<(NBKT + 255) / 256, 256, 0, stream>>>(ghist, NBKT);
    bhist_kernel<<<256, 256, 0, stream>>>(dst, ghist, E);
    bscan_kernel<<<1, 512, 0, stream>>>(ghist, bbase, gcursor);
    bin_kernel<<<NBIN_BLOCKS, 512, 0, stream>>>(src, dst, gcursor, packed, E);
    csr_bucket_kernel<<<NBKT, 256, 0, stream>>>(packed, bbase, rowptr, colx, dinv, E);
    w1t_kernel<<<(IND * HID + 255) / 256, 256, 0, stream>>>(W1, w1t);
    gemm1_mfma<<<(NN + 63) / 64, 256, 0, stream>>>(x, w1t, dinv, hs, NN);
    agg1_kernel<<<(NN * 32 + 255) / 256, 256, 0, stream>>>((const uint32*)hs, rowptr, colx, dinv, b1, h1);
    gemm2_kernel<<<(NN + 63) / 64, 256, 0, stream>>>(h1, W2, dinv, h2b, NN);
    agg2_kernel<<<(NN * 32 + 255) / 256, 256, 0, stream>>>((const uint32*)h2b, rowptr, colx, dinv, b2, out);
}